// Round 4
// baseline (172.014 us; speedup 1.0000x reference)
//
#include <hip/hip_runtime.h>
#include <math.h>

#define BB 64
#define SS 2048
#define FF 1024
#define HH 1024
#define NCHUNK 32
#define CHUNK_S 64    // SS/NCHUNK
#define RPW 16        // rows per wave (CHUNK_S/4)

// ---- workspace layout (float offsets) ----
#define WS_PL    0                        // 2048
#define WS_X     2048                     // 65536  : x[b][f] = attn_applied (row-major)
#define WS_X2    (WS_X+65536)             // 65536  : x2[b][j] (row-major)
#define WS_PACC  (WS_X2+65536)            // 2048*1024 = 2097152

__device__ __forceinline__ float sigm(float x){ return 1.f/(1.f + __expf(-x)); }

// ---------- B: fused scores + softmax accumulation; masked rows never loaded ----------
__global__ __launch_bounds__(256) void kB(const float* __restrict__ enc,
                                          const int*   __restrict__ mask,
                                          const float* __restrict__ attn_W,
                                          const float* __restrict__ input,
                                          const float* __restrict__ hidden,
                                          const float* __restrict__ attn_b,
                                          float* __restrict__ scores_out,
                                          float* __restrict__ pacc,
                                          float* __restrict__ pl)
{
    const int tid  = threadIdx.x;
    const int lane = tid & 63;
    const int w    = tid >> 6;
    const int b    = blockIdx.x >> 5;
    const int c    = blockIdx.x & 31;
    const int s0   = c*CHUNK_S + w*RPW;

    const float4* we4 = (const float4*)attn_W;
    const float4 we0 = we4[lane], we1 = we4[64+lane], we2 = we4[128+lane], we3 = we4[192+lane];

    // per-wave redundant base[b] = h.w_h + input*w_i + attn_b
    const float4* h4  = (const float4*)(hidden + (size_t)b*HH);
    const float4* wh4 = (const float4*)(attn_W + FF);
    float4 hv0 = h4[lane], hv1 = h4[64+lane], hv2 = h4[128+lane], hv3 = h4[192+lane];
    float4 wv0 = wh4[lane], wv1 = wh4[64+lane], wv2 = wh4[128+lane], wv3 = wh4[192+lane];
    float bp = hv0.x*wv0.x + hv0.y*wv0.y + hv0.z*wv0.z + hv0.w*wv0.w
             + hv1.x*wv1.x + hv1.y*wv1.y + hv1.z*wv1.z + hv1.w*wv1.w
             + hv2.x*wv2.x + hv2.y*wv2.y + hv2.z*wv2.z + hv2.w*wv2.w
             + hv3.x*wv3.x + hv3.y*wv3.y + hv3.z*wv3.z + hv3.w*wv3.w;
    #pragma unroll
    for (int off=32; off; off>>=1) bp += __shfl_xor(bp, off);
    const float bb = bp + input[b]*attn_W[FF+HH] + attn_b[0];

    float l = 0.f;
    float4 a0 = make_float4(0,0,0,0), a1 = a0, a2 = a0, a3 = a0;
    float sc_keep = 0.f;

    const float4* rowbase = (const float4*)(enc + (size_t)(b*SS + s0)*FF);
    const int* mrow = mask + b*SS + s0;

    for (int i=0;i<RPW;i++){
        if (mrow[i] != 0){
            const float4* row = rowbase + (size_t)i*(FF/4);
            float4 e0 = row[lane], e1 = row[64+lane], e2 = row[128+lane], e3 = row[192+lane];
            float d0 = e0.x*we0.x + e0.y*we0.y + e0.z*we0.z + e0.w*we0.w;
            float d1 = e1.x*we1.x + e1.y*we1.y + e1.z*we1.z + e1.w*we1.w;
            float d2 = e2.x*we2.x + e2.y*we2.y + e2.z*we2.z + e2.w*we2.w;
            float d3 = e3.x*we3.x + e3.y*we3.y + e3.z*we3.z + e3.w*we3.w;
            float dot = (d0+d1)+(d2+d3);
            #pragma unroll
            for (int off=32; off; off>>=1) dot += __shfl_xor(dot, off);
            float score = dot + bb;
            sc_keep = (lane == i) ? score : sc_keep;
            float p = __expf(score);
            l += p;
            a0.x += p*e0.x; a0.y += p*e0.y; a0.z += p*e0.z; a0.w += p*e0.w;
            a1.x += p*e1.x; a1.y += p*e1.y; a1.z += p*e1.z; a1.w += p*e1.w;
            a2.x += p*e2.x; a2.y += p*e2.y; a2.z += p*e2.z; a2.w += p*e2.w;
            a3.x += p*e3.x; a3.y += p*e3.y; a3.z += p*e3.z; a3.w += p*e3.w;
        } else {
            sc_keep = (lane == i) ? -1e10f : sc_keep;   // exp -> 0 exactly in kC
        }
    }
    if (lane < RPW) scores_out[b*SS + s0 + lane] = sc_keep;

    __shared__ float4 sacc[4][256];
    __shared__ float sl[4];
    if (lane==0) sl[w] = l;
    sacc[w][lane]     = a0;
    sacc[w][64+lane]  = a1;
    sacc[w][128+lane] = a2;
    sacc[w][192+lane] = a3;
    __syncthreads();
    float4 tot = sacc[0][tid];
    #pragma unroll
    for (int q=1;q<4;q++){ float4 u = sacc[q][tid]; tot.x+=u.x; tot.y+=u.y; tot.z+=u.z; tot.w+=u.w; }
    ((float4*)(pacc + (size_t)blockIdx.x*FF))[tid] = tot;
    if (tid==0) pl[blockIdx.x] = sl[0]+sl[1]+sl[2]+sl[3];
}

// ---------- C: merge partials -> x[b][f]; q==0: scores->weights; q==1: out init ----------
__global__ __launch_bounds__(256) void kC(const float* __restrict__ pacc,
                                          const float* __restrict__ pl,
                                          const float* __restrict__ out_b,
                                          float* __restrict__ x,
                                          float* __restrict__ wout,
                                          float* __restrict__ out)
{
    int b = blockIdx.x >> 2, q = blockIdx.x & 3, tid = threadIdx.x;
    float L = 0.f;
    #pragma unroll
    for (int c=0;c<NCHUNK;c++) L += pl[b*NCHUNK+c];
    float invL = 1.f/L;

    int f = q*256 + tid;
    float a = 0.f;
    #pragma unroll
    for (int c=0;c<NCHUNK;c++) a += pacc[((size_t)(b*NCHUNK+c))*FF + f];
    x[(size_t)b*FF + f] = a*invL;

    if (q == 0){
        for (int t = tid; t < SS; t += 256){
            int idx = b*SS + t;
            wout[idx] = __expf(wout[idx]) * invL;
        }
    } else if (q == 1){
        if (tid == 0) out[b] = out_b[0];
    }
}

// ---------- E: x2[b][j] = relu(x[b]·cW[j] + input[b]*cW[j][0] + cb[j]); scalar weight stream ----------
__global__ __launch_bounds__(256) void kE(const float* __restrict__ x,
                                          const float* __restrict__ input,
                                          const float* __restrict__ cW,
                                          const float* __restrict__ cb,
                                          float* __restrict__ x2)
{
    int lane = threadIdx.x & 63;
    int wu = __builtin_amdgcn_readfirstlane(threadIdx.x >> 6);
    int j = blockIdx.x*4 + wu;
    const float* wrow = cW + (size_t)j*(FF+1);
    const float4* xr = (const float4*)(x + (size_t)lane*FF);
    float acc = 0.f;
    #pragma unroll 8
    for (int k4=0; k4<FF/4; k4++){
        float4 xv = xr[k4];
        int k = 4*k4;
        acc += xv.x*wrow[1+k] + xv.y*wrow[2+k] + xv.z*wrow[3+k] + xv.w*wrow[4+k];
    }
    acc += input[lane]*wrow[0] + cb[j];
    x2[(size_t)lane*HH + j] = fmaxf(acc, 0.f);
}

// ---------- F: fused GRU — both matmuls (scalar weight streams), gates, h_new, out-projection ----------
__global__ __launch_bounds__(256) void kF(const float* __restrict__ x2,
                                          const float* __restrict__ hidden,
                                          const float* __restrict__ W_ih,
                                          const float* __restrict__ W_hh,
                                          const float* __restrict__ b_ih,
                                          const float* __restrict__ b_hh,
                                          const float* __restrict__ out_W,
                                          float* __restrict__ hnew,
                                          float* __restrict__ out)
{
    int lane = threadIdx.x & 63;
    int wu = __builtin_amdgcn_readfirstlane(threadIdx.x >> 6);
    int jl = wu >> 1;          // 0..1 : which output column this wave pair owns
    int kh = wu & 1;           // 0..1 : which k-half this wave computes
    int j = blockIdx.x*2 + jl;

    const float* wi0 = W_ih + (size_t)j*HH;
    const float* wi1 = W_ih + (size_t)(HH+j)*HH;
    const float* wi2 = W_ih + (size_t)(2*HH+j)*HH;
    const float* wh0 = W_hh + (size_t)j*HH;
    const float* wh1 = W_hh + (size_t)(HH+j)*HH;
    const float* wh2 = W_hh + (size_t)(2*HH+j)*HH;

    const float4* xr = (const float4*)(x2 + (size_t)lane*HH);
    const float4* hr = (const float4*)(hidden + (size_t)lane*HH);

    float ai0=0.f, ai1=0.f, ai2=0.f, ah0=0.f, ah1=0.f, ah2=0.f;
    int k4lo = kh*(HH/8), k4hi = k4lo + HH/8;   // 128 float4 iters per wave
    #pragma unroll 4
    for (int k4=k4lo; k4<k4hi; k4++){
        float4 xv = xr[k4], hv = hr[k4];
        int k = 4*k4;
        ai0 += xv.x*wi0[k] + xv.y*wi0[k+1] + xv.z*wi0[k+2] + xv.w*wi0[k+3];
        ai1 += xv.x*wi1[k] + xv.y*wi1[k+1] + xv.z*wi1[k+2] + xv.w*wi1[k+3];
        ai2 += xv.x*wi2[k] + xv.y*wi2[k+1] + xv.z*wi2[k+2] + xv.w*wi2[k+3];
        ah0 += hv.x*wh0[k] + hv.y*wh0[k+1] + hv.z*wh0[k+2] + hv.w*wh0[k+3];
        ah1 += hv.x*wh1[k] + hv.y*wh1[k+1] + hv.z*wh1[k+2] + hv.w*wh1[k+3];
        ah2 += hv.x*wh2[k] + hv.y*wh2[k+1] + hv.z*wh2[k+2] + hv.w*wh2[k+3];
    }

    __shared__ float sred[2][2][6][64];
    __shared__ float sout[2][64];
    sred[jl][kh][0][lane] = ai0; sred[jl][kh][1][lane] = ai1; sred[jl][kh][2][lane] = ai2;
    sred[jl][kh][3][lane] = ah0; sred[jl][kh][4][lane] = ah1; sred[jl][kh][5][lane] = ah2;
    __syncthreads();
    if (kh == 0){
        float g0 = sred[jl][0][0][lane] + sred[jl][1][0][lane];
        float g1 = sred[jl][0][1][lane] + sred[jl][1][1][lane];
        float g2 = sred[jl][0][2][lane] + sred[jl][1][2][lane];
        float g3 = sred[jl][0][3][lane] + sred[jl][1][3][lane];
        float g4 = sred[jl][0][4][lane] + sred[jl][1][4][lane];
        float g5 = sred[jl][0][5][lane] + sred[jl][1][5][lane];
        float r = sigm(g0+b_ih[j]       + g3+b_hh[j]);
        float z = sigm(g1+b_ih[HH+j]    + g4+b_hh[HH+j]);
        float n = tanhf(g2+b_ih[2*HH+j] + r*(g5+b_hh[2*HH+j]));
        float hold = hidden[(size_t)lane*HH + j];
        float hn = (1.f - z)*n + z*hold;
        hnew[(size_t)lane*HH + j] = hn;
        sout[jl][lane] = fmaxf(hn, 0.f) * out_W[j];
    }
    __syncthreads();
    if (wu == 0) atomicAdd(out + lane, sout[0][lane] + sout[1][lane]);
}

extern "C" void kernel_launch(void* const* d_in, const int* in_sizes, int n_in,
                              void* d_out, int out_size, void* d_ws, size_t ws_size,
                              hipStream_t stream) {
    const float* input     = (const float*)d_in[0];
    const float* hidden    = (const float*)d_in[1];
    const float* enc       = (const float*)d_in[2];
    const int*   mask      = (const int*)  d_in[3];
    const float* attn_W    = (const float*)d_in[4];
    const float* attn_b    = (const float*)d_in[5];
    const float* combine_W = (const float*)d_in[6];
    const float* combine_b = (const float*)d_in[7];
    const float* W_ih      = (const float*)d_in[8];
    const float* W_hh      = (const float*)d_in[9];
    const float* b_ih      = (const float*)d_in[10];
    const float* b_hh      = (const float*)d_in[11];
    const float* out_W     = (const float*)d_in[12];
    const float* out_b     = (const float*)d_in[13];

    float* out  = (float*)d_out;
    float* hnew = out + 64;            // (1,B,H)
    float* attw = out + 64 + BB*HH;    // (B,S,1) — raw scores between kB and kC
    float* ws   = (float*)d_ws;

    kB <<<BB*NCHUNK, 256, 0, stream>>>(enc, mask, attn_W, input, hidden, attn_b,
                                       attw, ws+WS_PACC, ws+WS_PL);
    kC <<<256, 256, 0, stream>>>(ws+WS_PACC, ws+WS_PL, out_b, ws+WS_X, attw, out);
    kE <<<256, 256, 0, stream>>>(ws+WS_X, input, combine_W, combine_b, ws+WS_X2);
    kF <<<512, 256, 0, stream>>>(ws+WS_X2, hidden, W_ih, W_hh, b_ih, b_hh, out_W, hnew, out);
}